// Round 8
// baseline (139.105 us; speedup 1.0000x reference)
//
#include <hip/hip_runtime.h>
#include <hip/hip_fp16.h>

#define BS 2
#define NS 50000
#define CCH 32
#define RR 128
#define SS 8

typedef float v2f __attribute__((ext_vector_type(2)));

// ws layout:
//   tp : BS*3*RR*RR*CCH halfs (fp16 transposed planes, [b][pl][y][x][c]) = 6,291,456 B
//   Wc : 1024 floats  (W_v @ W_out)
//   bvw: 32 floats    (b_v @ W_out)

// blocks 0..767: transpose+convert one (b,pl,y) row through LDS (32c x 128x tile).
// blocks 768..771: compute Wc = Wv@Wout and bvw = bv@Wout.
__global__ __launch_bounds__(256)
void prep(const float* __restrict__ cxz,
          const float* __restrict__ cxy,
          const float* __restrict__ cyz,
          const float* __restrict__ Wv, const float* __restrict__ bv,
          const float* __restrict__ Wout,
          unsigned short* __restrict__ tp, float* __restrict__ Wc,
          float* __restrict__ bvw) {
    __shared__ float lds[32 * 129];
    int tid = threadIdx.x;
    int row = blockIdx.x;
    if (row < BS * 3 * RR) {
        int y  = row & 127;
        int pl = (row >> 7) % 3;
        int b  = row / 384;
        const float* src = (pl == 0) ? cxz : ((pl == 1) ? cxy : cyz);
        const float* sp = src + (((size_t)(b * CCH)) << 14) + (y << 7);
#pragma unroll
        for (int i = 0; i < 16; ++i) {
            int c = (tid >> 7) + 2 * i;
            int x = tid & 127;
            lds[c * 129 + x] = sp[((size_t)c << 14) + x];
        }
        __syncthreads();
        ushort2* dst = (ushort2*)(tp + ((size_t)row << 12));
#pragma unroll
        for (int i = 0; i < 8; ++i) {
            int c2 = tid & 15;                 // channel pair
            int x  = (tid >> 4) + 16 * i;
            ushort2 v;
            v.x = __half_as_ushort(__float2half(lds[(2 * c2) * 129 + x]));
            v.y = __half_as_ushort(__float2half(lds[(2 * c2 + 1) * 129 + x]));
            dst[(x << 4) + c2] = v;
        }
    } else {
        int t = (row - BS * 3 * RR) * 256 + tid;   // 0..1023
        int c = t >> 5, j = t & 31;
        float acc = 0.f;
#pragma unroll
        for (int k = 0; k < 32; ++k) acc += Wv[c * 32 + k] * Wout[k * 32 + j];
        Wc[t] = acc;
        if (t < 32) {
            float a2 = 0.f;
#pragma unroll
            for (int k = 0; k < 32; ++k) a2 += bv[k] * Wout[k * 32 + t];
            bvw[t] = a2;
        }
    }
}

// ---- main kernel: 4 lanes/query (16 queries/wave), lane holds channels 8l..8l+7 ----
// Plane layout (fp16, as uint4*): plane stride 1<<16, y stride 1<<9, x stride 1<<2.

struct f8 { v2f a[4]; };

// one sample's in-flight state: 12 taps + 3 axis fracs (weights recomputed at eval)
struct Samp { uint4 u[12]; float f0, f1, f2; };

// acc += w * f16x8(u) — fmaf(fpext(f16), f32, f32) folds to v_fma_mix_f32
__device__ __forceinline__ void acc8(f8& acc, uint4 u, float w) {
    __half2 h0 = __builtin_bit_cast(__half2, u.x);
    __half2 h1 = __builtin_bit_cast(__half2, u.y);
    __half2 h2 = __builtin_bit_cast(__half2, u.z);
    __half2 h3 = __builtin_bit_cast(__half2, u.w);
    acc.a[0].x = fmaf(__half2float(h0.x), w, acc.a[0].x);
    acc.a[0].y = fmaf(__half2float(h0.y), w, acc.a[0].y);
    acc.a[1].x = fmaf(__half2float(h1.x), w, acc.a[1].x);
    acc.a[1].y = fmaf(__half2float(h1.y), w, acc.a[1].y);
    acc.a[2].x = fmaf(__half2float(h2.x), w, acc.a[2].x);
    acc.a[2].y = fmaf(__half2float(h2.y), w, acc.a[2].y);
    acc.a[3].x = fmaf(__half2float(h3.x), w, acc.a[3].x);
    acc.a[3].y = fmaf(__half2float(h3.y), w, acc.a[3].y);
}

// quantize one axis once; reused by the two planes that consume it
__device__ __forceinline__ void axq(float p, int& i0, int& i1, float& w) {
    float x = fminf(fmaxf(p, 0.f), 1.f) * 127.f;
    float f = floorf(x);
    i0 = (int)f;
    i1 = min(i0 + 1, 127);
    w = x - f;
}

// issue all 12 tap loads for one sample (no eval — keeps them in flight)
__device__ __forceinline__ Samp load_samp(const uint4* __restrict__ P0,
                                          float p0, float p1, float p2) {
    Samp t;
    int i00, i01, i10, i11, i20, i21;
    axq(p0, i00, i01, t.f0);
    axq(p1, i10, i11, t.f1);
    axq(p2, i20, i21, t.f2);
    const uint4* Pxz = P0;
    const uint4* Pxy = P0 + (1 << 16);
    const uint4* Pyz = P0 + (2 << 16);
    int c00 = i00 << 2, c01 = i01 << 2;          // axis0 cols
    int c10 = i10 << 2, c11 = i11 << 2;          // axis1 cols
    int r10 = i10 << 9, r11 = i11 << 9;          // axis1 rows
    int r20 = i20 << 9, r21 = i21 << 9;          // axis2 rows
    t.u[0]  = Pxz[r20 + c00];  t.u[1]  = Pxz[r20 + c01];
    t.u[2]  = Pxz[r21 + c00];  t.u[3]  = Pxz[r21 + c01];
    t.u[4]  = Pxy[r10 + c00];  t.u[5]  = Pxy[r10 + c01];
    t.u[6]  = Pxy[r11 + c00];  t.u[7]  = Pxy[r11 + c01];
    t.u[8]  = Pyz[r20 + c10];  t.u[9]  = Pyz[r20 + c11];
    t.u[10] = Pyz[r21 + c10];  t.u[11] = Pyz[r21 + c11];
    return t;
}

__device__ __forceinline__ void eval_plane(f8& acc, const uint4* u,
                                           float wx, float wy) {
    float w11 = wx * wy;
    float w01 = wx - w11;          // wx*(1-wy)
    float w10 = wy - w11;          // (1-wx)*wy
    float w00 = 1.f - wx - w10;    // (1-wx)*(1-wy)
    acc8(acc, u[0], w00);
    acc8(acc, u[1], w01);
    acc8(acc, u[2], w10);
    acc8(acc, u[3], w11);
}

__device__ __forceinline__ void eval_samp(const Samp& t, f8& acc) {
    eval_plane(acc, t.u + 0, t.f0, t.f2);   // XZ
    eval_plane(acc, t.u + 4, t.f0, t.f1);   // XY
    eval_plane(acc, t.u + 8, t.f1, t.f2);   // YZ
}

// element idx (0..7 within lane) of f8; compile-time idx.
#define GETE(v, idx) (((idx) & 1) ? (v).a[((idx) >> 1) & 3].y : (v).a[((idx) >> 1) & 3].x)
// broadcast channel idx (0..31) across the 4-lane query group (base = tid & 60).
#define GETC(v, idx) __shfl(GETE(v, idx), base | ((idx) >> 3), 64)

__global__ __launch_bounds__(128)
void eda_main(const float* __restrict__ qp, const unsigned short* __restrict__ tp,
              const float* __restrict__ Woff, const float* __restrict__ boff,
              const float* __restrict__ Ww, const float* __restrict__ bw,
              const float* __restrict__ Wc, const float* __restrict__ bvw,
              const float* __restrict__ bout, float* __restrict__ out) {
    __shared__ v2f sWcat[32][4][4];   // [k][lane][e]: j<24 -> W_off, else W_w
    __shared__ v2f sWc[32][4][4];     // [k][lane][e]: W_v@W_out
    __shared__ float sbcat[32];
    __shared__ float sbvw[32];
    __shared__ float sbout[32];

    int tid = threadIdx.x;
    int lane = tid & 3;
    int base = tid & 60;                          // query-group base within wave
    int b  = blockIdx.x & 1;                      // XCD-parity batch split
    int qi = (blockIdx.x >> 1) * 32 + (tid >> 2); // query within batch
    int qq = min(qi, NS - 1);

    const float* p = qp + ((size_t)b * NS + qq) * 3;
    float p0 = p[0], p1 = p[1], p2 = p[2];

    const uint4* P0 = (const uint4*)tp + (((size_t)(b * 3)) << 16) + lane;

    // ---- issue feature tap loads EARLY; they fly during LDS weight staging ----
    Samp fs = load_samp(P0, p0, p1, p2);

    for (int i = tid; i < 1024; i += 128) {
        int k = i >> 5, j = i & 31;
        ((float*)sWcat)[i] = (j < 24) ? Woff[k * 24 + j] : Ww[k * 8 + (j - 24)];
        ((float*)sWc)[i]   = Wc[i];
    }
    if (tid < 32) {
        sbcat[tid] = (tid < 24) ? boff[tid] : bw[tid - 24];
        sbvw[tid]  = bvw[tid];
        sbout[tid] = bout[tid];
    }
    __syncthreads();

    // ---- feature ----
    f8 feat = {};
    eval_samp(fs, feat);

    // ---- cat = feature @ [W_off | W_w] + bias ----
    f8 cat;
#pragma unroll
    for (int e = 0; e < 4; ++e) {
        cat.a[e].x = sbcat[(lane << 3) + 2 * e];
        cat.a[e].y = sbcat[(lane << 3) + 2 * e + 1];
    }
#pragma unroll
    for (int k = 0; k < 32; ++k) {
        float fc = GETC(feat, k);
        v2f fc2 = {fc, fc};
#pragma unroll
        for (int e = 0; e < 4; ++e)
            cat.a[e] = __builtin_elementwise_fma(fc2, sWcat[k][lane][e], cat.a[e]);
    }

    // ---- software-pipelined s-loop: prefetch s+1's taps during s's eval ----
    f8 wa = {};
    float wsum = 0.f;
    float w_cur = GETC(cat, 24);
    Samp cur = load_samp(P0, p0 + GETC(cat, 0), p1 + GETC(cat, 1), p2 + GETC(cat, 2));
    Samp nxt;
    float w_nxt;
#pragma unroll
    for (int s = 0; s < SS; ++s) {
        if (s < SS - 1) {
            w_nxt = GETC(cat, 24 + (s + 1));
            nxt = load_samp(P0, p0 + GETC(cat, 3 * (s + 1) + 0),
                                p1 + GETC(cat, 3 * (s + 1) + 1),
                                p2 + GETC(cat, 3 * (s + 1) + 2));
        }
        f8 aux = {};
        eval_samp(cur, aux);
        v2f w2 = {w_cur, w_cur};
#pragma unroll
        for (int e = 0; e < 4; ++e)
            wa.a[e] = __builtin_elementwise_fma(w2, aux.a[e], wa.a[e]);
        wsum += w_cur;
        if (s < SS - 1) { cur = nxt; w_cur = w_nxt; }
    }

    // ---- out = wa @ (W_v@W_out) + wsum*(b_v@W_out) + b_out + feature ----
    f8 o;
    v2f ws2 = {wsum, wsum};
#pragma unroll
    for (int e = 0; e < 4; ++e) {
        v2f bo  = {sbout[(lane << 3) + 2 * e], sbout[(lane << 3) + 2 * e + 1]};
        v2f bv2 = {sbvw[(lane << 3) + 2 * e], sbvw[(lane << 3) + 2 * e + 1]};
        o.a[e] = __builtin_elementwise_fma(ws2, bv2, bo) + feat.a[e];
    }
#pragma unroll
    for (int k = 0; k < 32; ++k) {
        float wc = GETC(wa, k);
        v2f wc2 = {wc, wc};
#pragma unroll
        for (int e = 0; e < 4; ++e)
            o.a[e] = __builtin_elementwise_fma(wc2, sWc[k][lane][e], o.a[e]);
    }

    if (qi < NS) {
        float* dst = out + ((size_t)b * NS + qi) * 32 + (lane << 3);
        *(float4*)dst       = make_float4(o.a[0].x, o.a[0].y, o.a[1].x, o.a[1].y);
        *(float4*)(dst + 4) = make_float4(o.a[2].x, o.a[2].y, o.a[3].x, o.a[3].y);
    }
}

extern "C" void kernel_launch(void* const* d_in, const int* in_sizes, int n_in,
                              void* d_out, int out_size, void* d_ws, size_t ws_size,
                              hipStream_t stream) {
    const float* qp   = (const float*)d_in[0];
    const float* cxz  = (const float*)d_in[1];
    const float* cxy  = (const float*)d_in[2];
    const float* cyz  = (const float*)d_in[3];
    const float* Woff = (const float*)d_in[4];
    const float* boff = (const float*)d_in[5];
    const float* Ww   = (const float*)d_in[6];
    const float* bw   = (const float*)d_in[7];
    const float* Wv   = (const float*)d_in[8];
    const float* bv   = (const float*)d_in[9];
    const float* Wout = (const float*)d_in[10];
    const float* bout = (const float*)d_in[11];
    float* out = (float*)d_out;

    unsigned short* tp = (unsigned short*)d_ws;
    float* Wc  = (float*)((char*)d_ws + (size_t)BS * 3 * RR * RR * CCH * 2);
    float* bvw = Wc + 1024;

    prep<<<BS * 3 * RR + 4, 256, 0, stream>>>(cxz, cxy, cyz, Wv, bv, Wout, tp, Wc, bvw);
    // even blockIdx -> batch 0, odd -> batch 1 (round-robin block->XCD dispatch
    // keeps each XCD on one batch's 3.1 MB fp16 planes -> L2-resident taps).
    int blocks_per_batch = (NS + 31) / 32;   // 32 queries per 128-thread block
    eda_main<<<2 * blocks_per_batch, 128, 0, stream>>>(qp, tp, Woff, boff, Ww, bw,
                                                       Wc, bvw, bout, out);
}